// Round 3
// baseline (822.587 us; speedup 1.0000x reference)
//
#include <hip/hip_runtime.h>

#define BLOCK 256
#define RPB 128   // rows per block (2 threads per row)

// dot of float4 W_ with 4 consecutive elems of X_ starting at 4*J_ (all compile-time)
#define DOT4(X_, J_, W_) (X_[4*(J_)]*W_.x + X_[4*(J_)+1]*W_.y + X_[4*(J_)+2]*W_.z + X_[4*(J_)+3]*W_.w)

__launch_bounds__(BLOCK, 2)
__global__ void msfe_kernel(
    const float* __restrict__ f1, const float* __restrict__ f4, const float* __restrict__ fD,
    const float* __restrict__ Wp, const float* __restrict__ bp,
    const float* __restrict__ ln_g, const float* __restrict__ ln_b,
    const float* __restrict__ Wq, const float* __restrict__ bq,
    const float* __restrict__ Wk, const float* __restrict__ bk,
    const float* __restrict__ Wv, const float* __restrict__ bv,
    const float* __restrict__ Wo1, const float* __restrict__ bo1,
    const float* __restrict__ Wo2, const float* __restrict__ bo2,
    float* __restrict__ out, int nRows)
{
    __shared__ float Wp_l[8192];
    __shared__ float Wq_l[1024], Wk_l[1024], A_l[1024];
    __shared__ float Wv_l[1024], Wo1_l[1024], Wo2_l[1024];
    __shared__ float bp_l[32], g_l[32], b_l[32], u_l[32], v_l[32];
    __shared__ float bv_l[32], bo1_l[32], bo2_l[32];
    __shared__ float c_l;

    const int tid = threadIdx.x;

    // ---- stage weights (coalesced float4) ----
    #pragma unroll
    for (int i = 0; i < 8; ++i)
        ((float4*)Wp_l)[tid + i * BLOCK] = ((const float4*)Wp)[tid + i * BLOCK];
    ((float4*)Wq_l)[tid]  = ((const float4*)Wq)[tid];
    ((float4*)Wk_l)[tid]  = ((const float4*)Wk)[tid];
    ((float4*)Wv_l)[tid]  = ((const float4*)Wv)[tid];
    ((float4*)Wo1_l)[tid] = ((const float4*)Wo1)[tid];
    ((float4*)Wo2_l)[tid] = ((const float4*)Wo2)[tid];
    if (tid < 32) {
        bp_l[tid] = bp[tid]; g_l[tid] = ln_g[tid]; b_l[tid] = ln_b[tid];
        bv_l[tid] = bv[tid]; bo1_l[tid] = bo1[tid]; bo2_l[tid] = bo2[tid];
    }
    __syncthreads();

    // ---- build scaled attention matrices: A = Wq^T Wk /sqrt(D), u, v, c ----
    const float isq = 0.17677669529663688f; // 1/sqrt(32)
    {
        const int i = tid & 31, jb = (tid >> 5) * 4;
        float s0 = 0.f, s1 = 0.f, s2 = 0.f, s3 = 0.f;
        #pragma unroll
        for (int d = 0; d < 32; ++d) {
            float wq = Wq_l[d * 32 + i];
            s0 += wq * Wk_l[d * 32 + jb];
            s1 += wq * Wk_l[d * 32 + jb + 1];
            s2 += wq * Wk_l[d * 32 + jb + 2];
            s3 += wq * Wk_l[d * 32 + jb + 3];
        }
        A_l[i * 32 + jb]     = s0 * isq;
        A_l[i * 32 + jb + 1] = s1 * isq;
        A_l[i * 32 + jb + 2] = s2 * isq;
        A_l[i * 32 + jb + 3] = s3 * isq;
    }
    if (tid < 32) {
        float s = 0.f;
        #pragma unroll
        for (int d = 0; d < 32; ++d) s += bq[d] * Wk_l[d * 32 + tid];
        u_l[tid] = s * isq;
    } else if (tid < 64) {
        const int i = tid - 32; float s = 0.f;
        #pragma unroll
        for (int d = 0; d < 32; ++d) s += Wq_l[d * 32 + i] * bk[d];
        v_l[i] = s * isq;
    } else if (tid == 64) {
        float s = 0.f;
        #pragma unroll
        for (int d = 0; d < 32; ++d) s += bq[d] * bk[d];
        c_l = s * isq;
    }
    __syncthreads();

    const int row  = blockIdx.x * RPB + (tid >> 1);
    const int half = tid & 1;
    if (row >= nRows) return;

    const float* __restrict__ p0 = f1 + (size_t)row * 256 + half * 128;
    const float* __restrict__ p1 = f4 + (size_t)row * 256 + half * 128;
    const float* __restrict__ p2 = fD + (size_t)row * 256 + half * 128;
    const float* __restrict__ wb = Wp_l + half * 128;

    // ---- Phase A: partial projection over this thread's 128 k-elems ----
    float acc0[32], acc1[32], acc2[32];
    #pragma unroll
    for (int d = 0; d < 32; ++d) { acc0[d] = 0.f; acc1[d] = 0.f; acc2[d] = 0.f; }

    // 1-deep prefetch rotation
    float4 n0a = *(const float4*)(p0),     n0b = *(const float4*)(p0 + 4);
    float4 n1a = *(const float4*)(p1),     n1b = *(const float4*)(p1 + 4);
    float4 n2a = *(const float4*)(p2),     n2b = *(const float4*)(p2 + 4);
    #pragma unroll 1
    for (int kc = 0; kc < 128; kc += 8) {
        float4 a0 = n0a, a0b = n0b, a1 = n1a, a1b = n1b, a2 = n2a, a2b = n2b;
        const int kn = (kc + 8 < 128) ? kc + 8 : kc;  // last iter reloads (L1 hit)
        n0a = *(const float4*)(p0 + kn); n0b = *(const float4*)(p0 + kn + 4);
        n1a = *(const float4*)(p1 + kn); n1b = *(const float4*)(p1 + kn + 4);
        n2a = *(const float4*)(p2 + kn); n2b = *(const float4*)(p2 + kn + 4);
        #pragma unroll
        for (int d = 0; d < 32; ++d) {
            const float* wr = wb + d * 256 + kc;
            float4 w  = *(const float4*)(wr);
            float4 w2 = *(const float4*)(wr + 4);
            acc0[d] += a0.x*w.x + a0.y*w.y + a0.z*w.z + a0.w*w.w
                     + a0b.x*w2.x + a0b.y*w2.y + a0b.z*w2.z + a0b.w*w2.w;
            acc1[d] += a1.x*w.x + a1.y*w.y + a1.z*w.z + a1.w*w.w
                     + a1b.x*w2.x + a1b.y*w2.y + a1b.z*w2.z + a1b.w*w2.w;
            acc2[d] += a2.x*w.x + a2.y*w.y + a2.z*w.z + a2.w*w.w
                     + a2b.x*w2.x + a2b.y*w2.y + a2b.z*w2.z + a2b.w*w2.w;
        }
    }

    // ---- pair reduce: both lanes get the full row dot ----
    #pragma unroll
    for (int d = 0; d < 32; ++d) {
        acc0[d] += __shfl_xor(acc0[d], 1);
        acc1[d] += __shfl_xor(acc1[d], 1);
        acc2[d] += __shfl_xor(acc2[d], 1);
    }

    // ---- relu + LayerNorm -> X[3][32] (replicated on both lanes) ----
    float X[3][32];
#define LNORM(ACC_, S_)                                                    \
    {                                                                      \
        float sum = 0.f, sq = 0.f;                                         \
        _Pragma("unroll")                                                  \
        for (int d = 0; d < 32; ++d) {                                     \
            float h = fmaxf(ACC_[d] + bp_l[d], 0.f);                       \
            ACC_[d] = h; sum += h; sq += h * h;                            \
        }                                                                  \
        float mu  = sum * 0.03125f;                                        \
        float var = sq * 0.03125f - mu * mu;                               \
        float inv = rsqrtf(var + 1e-5f);                                   \
        _Pragma("unroll")                                                  \
        for (int d = 0; d < 32; ++d)                                       \
            X[S_][d] = g_l[d] * (ACC_[d] - mu) * inv + b_l[d];             \
    }
    LNORM(acc0, 0)
    LNORM(acc1, 1)
    LNORM(acc2, 2)
#undef LNORM

    // ---- scores: sc[s][t] = X_s^T A X_t + u.X_t + v.X_s + c  (replicated, const idx) ----
    float uX[3], vX[3];
    #pragma unroll
    for (int t = 0; t < 3; ++t) {
        float us = 0.f, vs = 0.f;
        #pragma unroll
        for (int e = 0; e < 32; ++e) {
            us += u_l[e] * X[t][e];
            vs += v_l[e] * X[t][e];
        }
        uX[t] = us; vX[t] = vs;
    }
    float sc[3][3];
    #pragma unroll
    for (int t = 0; t < 3; ++t) {
        float Z[32];
        #pragma unroll
        for (int i = 0; i < 32; ++i) {
            const float4* ar = (const float4*)(A_l + i * 32);
            float z = 0.f;
            #pragma unroll
            for (int j = 0; j < 8; ++j) {
                float4 a = ar[j];
                z += DOT4(X[t], j, a);
            }
            Z[i] = z;
        }
        #pragma unroll
        for (int s = 0; s < 3; ++s) {
            float p = 0.f;
            #pragma unroll
            for (int e = 0; e < 32; ++e) p += X[s][e] * Z[e];
            sc[s][t] = p + uX[t] + vX[s] + c_l;
        }
    }

    // ---- softmax rows; g_t = (1/3) sum_s w[s][t] ----
    float g0 = 0.f, g1 = 0.f, g2 = 0.f;
    #pragma unroll
    for (int s = 0; s < 3; ++s) {
        float m  = fmaxf(sc[s][0], fmaxf(sc[s][1], sc[s][2]));
        float e0 = __expf(sc[s][0] - m), e1 = __expf(sc[s][1] - m), e2 = __expf(sc[s][2] - m);
        float r  = 1.f / (e0 + e1 + e2);
        g0 += e0 * r; g1 += e1 * r; g2 += e2 * r;
    }
    g0 *= (1.f / 3.f); g1 *= (1.f / 3.f); g2 *= (1.f / 3.f);

    // xb = g0*X0 + g1*X1 + g2*X2  (softmax rows sum to 1 -> V fold)
    float xb[32];
    #pragma unroll
    for (int e = 0; e < 32; ++e)
        xb[e] = g0 * X[0][e] + g1 * X[1][e] + g2 * X[2][e];

#define MATVEC(W_, BIAS_, IN_, OUT_)                                       \
    _Pragma("unroll")                                                      \
    for (int d = 0; d < 32; ++d) {                                         \
        const float4* wr = (const float4*)(W_ + d * 32);                   \
        float p = BIAS_[d];                                                \
        _Pragma("unroll")                                                  \
        for (int j = 0; j < 8; ++j) {                                      \
            float4 w = wr[j];                                              \
            p += DOT4(IN_, j, w);                                          \
        }                                                                  \
        OUT_[d] = p;                                                       \
    }

    // pooled = xb @ Wv^T + bv
    float pooled[32];
    MATVEC(Wv_l, bv_l, xb, pooled)

    // h1 = relu(pooled @ Wo1^T + bo1)
    float h1[32];
    MATVEC(Wo1_l, bo1_l, pooled, h1)
    #pragma unroll
    for (int d = 0; d < 32; ++d) h1[d] = fmaxf(h1[d], 0.f);

    // o = h1 @ Wo2^T + bo2 + pooled
    float o[32];
    MATVEC(Wo2_l, bo2_l, h1, o)
    #pragma unroll
    for (int d = 0; d < 32; ++d) o[d] += pooled[d];
#undef MATVEC

    // ---- store: each lane writes its half with COMPILE-TIME indices ----
    float4* op = (float4*)(out + (size_t)row * 32);
    if (half == 0) {
        op[0] = make_float4(o[0],  o[1],  o[2],  o[3]);
        op[1] = make_float4(o[4],  o[5],  o[6],  o[7]);
        op[2] = make_float4(o[8],  o[9],  o[10], o[11]);
        op[3] = make_float4(o[12], o[13], o[14], o[15]);
    } else {
        op[4] = make_float4(o[16], o[17], o[18], o[19]);
        op[5] = make_float4(o[20], o[21], o[22], o[23]);
        op[6] = make_float4(o[24], o[25], o[26], o[27]);
        op[7] = make_float4(o[28], o[29], o[30], o[31]);
    }
}

extern "C" void kernel_launch(void* const* d_in, const int* in_sizes, int n_in,
                              void* d_out, int out_size, void* d_ws, size_t ws_size,
                              hipStream_t stream) {
    const float* f1   = (const float*)d_in[0];
    const float* f4   = (const float*)d_in[1];
    const float* fD   = (const float*)d_in[2];
    const float* Wp   = (const float*)d_in[3];
    const float* bp   = (const float*)d_in[4];
    const float* ln_g = (const float*)d_in[5];
    const float* ln_b = (const float*)d_in[6];
    const float* Wq   = (const float*)d_in[7];
    const float* bq   = (const float*)d_in[8];
    const float* Wk   = (const float*)d_in[9];
    const float* bk   = (const float*)d_in[10];
    const float* Wv   = (const float*)d_in[11];
    const float* bv   = (const float*)d_in[12];
    const float* Wo1  = (const float*)d_in[13];
    const float* bo1  = (const float*)d_in[14];
    const float* Wo2  = (const float*)d_in[15];
    const float* bo2  = (const float*)d_in[16];

    const int nRows  = in_sizes[0] / 256;
    const int blocks = (nRows + RPB - 1) / RPB;

    msfe_kernel<<<blocks, BLOCK, 0, stream>>>(
        f1, f4, fD, Wp, bp, ln_g, ln_b, Wq, bq, Wk, bk, Wv, bv,
        Wo1, bo1, Wo2, bo2, (float*)d_out, nRows);
}

// Round 4
// 811.907 us; speedup vs baseline: 1.0132x; 1.0132x over previous
//
#include <hip/hip_runtime.h>

#define BLOCK 256
#define RPB 128   // rows per block (2 threads per row)

// dot of float4 W_ with 4 consecutive elems of X_ starting at 4*J_ (all compile-time)
#define DOT4(X_, J_, W_) (X_[4*(J_)]*W_.x + X_[4*(J_)+1]*W_.y + X_[4*(J_)+2]*W_.z + X_[4*(J_)+3]*W_.w)

// min-waves/EU = 1 -> VGPR cap 256 (the (.,2) variant capped at 128 and spilled 827 MB)
__launch_bounds__(BLOCK, 1)
__global__ void msfe_kernel(
    const float* __restrict__ f1, const float* __restrict__ f4, const float* __restrict__ fD,
    const float* __restrict__ Wp, const float* __restrict__ bp,
    const float* __restrict__ ln_g, const float* __restrict__ ln_b,
    const float* __restrict__ Wq, const float* __restrict__ bq,
    const float* __restrict__ Wk, const float* __restrict__ bk,
    const float* __restrict__ Wv, const float* __restrict__ bv,
    const float* __restrict__ Wo1, const float* __restrict__ bo1,
    const float* __restrict__ Wo2, const float* __restrict__ bo2,
    float* __restrict__ out, int nRows)
{
    __shared__ float Wp_l[8192];
    __shared__ float Wq_l[1024], Wk_l[1024], A_l[1024];
    __shared__ float Wv_l[1024], Wo1_l[1024], Wo2_l[1024];
    __shared__ float bp_l[32], g_l[32], b_l[32], u_l[32], v_l[32];
    __shared__ float bv_l[32], bo1_l[32], bo2_l[32];
    __shared__ float c_l;

    const int tid = threadIdx.x;

    // ---- stage weights (coalesced float4) ----
    #pragma unroll
    for (int i = 0; i < 8; ++i)
        ((float4*)Wp_l)[tid + i * BLOCK] = ((const float4*)Wp)[tid + i * BLOCK];
    ((float4*)Wq_l)[tid]  = ((const float4*)Wq)[tid];
    ((float4*)Wk_l)[tid]  = ((const float4*)Wk)[tid];
    ((float4*)Wv_l)[tid]  = ((const float4*)Wv)[tid];
    ((float4*)Wo1_l)[tid] = ((const float4*)Wo1)[tid];
    ((float4*)Wo2_l)[tid] = ((const float4*)Wo2)[tid];
    if (tid < 32) {
        bp_l[tid] = bp[tid]; g_l[tid] = ln_g[tid]; b_l[tid] = ln_b[tid];
        bv_l[tid] = bv[tid]; bo1_l[tid] = bo1[tid]; bo2_l[tid] = bo2[tid];
    }
    __syncthreads();

    // ---- build scaled attention matrices: A = Wq^T Wk /sqrt(D), u, v, c ----
    const float isq = 0.17677669529663688f; // 1/sqrt(32)
    {
        const int i = tid & 31, jb = (tid >> 5) * 4;
        float s0 = 0.f, s1 = 0.f, s2 = 0.f, s3 = 0.f;
        #pragma unroll
        for (int d = 0; d < 32; ++d) {
            float wq = Wq_l[d * 32 + i];
            s0 += wq * Wk_l[d * 32 + jb];
            s1 += wq * Wk_l[d * 32 + jb + 1];
            s2 += wq * Wk_l[d * 32 + jb + 2];
            s3 += wq * Wk_l[d * 32 + jb + 3];
        }
        A_l[i * 32 + jb]     = s0 * isq;
        A_l[i * 32 + jb + 1] = s1 * isq;
        A_l[i * 32 + jb + 2] = s2 * isq;
        A_l[i * 32 + jb + 3] = s3 * isq;
    }
    if (tid < 32) {
        float s = 0.f;
        #pragma unroll
        for (int d = 0; d < 32; ++d) s += bq[d] * Wk_l[d * 32 + tid];
        u_l[tid] = s * isq;
    } else if (tid < 64) {
        const int i = tid - 32; float s = 0.f;
        #pragma unroll
        for (int d = 0; d < 32; ++d) s += Wq_l[d * 32 + i] * bk[d];
        v_l[i] = s * isq;
    } else if (tid == 64) {
        float s = 0.f;
        #pragma unroll
        for (int d = 0; d < 32; ++d) s += bq[d] * bk[d];
        c_l = s * isq;
    }
    __syncthreads();

    const int row  = blockIdx.x * RPB + (tid >> 1);
    const int half = tid & 1;
    if (row >= nRows) return;

    const float* __restrict__ p0 = f1 + (size_t)row * 256 + half * 128;
    const float* __restrict__ p1 = f4 + (size_t)row * 256 + half * 128;
    const float* __restrict__ p2 = fD + (size_t)row * 256 + half * 128;
    const float* __restrict__ wb = Wp_l + half * 128;

    // ---- Phase A: partial projection over this thread's 128 k-elems ----
    float acc0[32], acc1[32], acc2[32];
    #pragma unroll
    for (int d = 0; d < 32; ++d) { acc0[d] = 0.f; acc1[d] = 0.f; acc2[d] = 0.f; }

    // 1-deep prefetch rotation
    float4 n0a = *(const float4*)(p0),     n0b = *(const float4*)(p0 + 4);
    float4 n1a = *(const float4*)(p1),     n1b = *(const float4*)(p1 + 4);
    float4 n2a = *(const float4*)(p2),     n2b = *(const float4*)(p2 + 4);
    #pragma unroll 1
    for (int kc = 0; kc < 128; kc += 8) {
        float4 a0 = n0a, a0b = n0b, a1 = n1a, a1b = n1b, a2 = n2a, a2b = n2b;
        const int kn = (kc + 8 < 128) ? kc + 8 : kc;  // last iter reloads (L1 hit)
        n0a = *(const float4*)(p0 + kn); n0b = *(const float4*)(p0 + kn + 4);
        n1a = *(const float4*)(p1 + kn); n1b = *(const float4*)(p1 + kn + 4);
        n2a = *(const float4*)(p2 + kn); n2b = *(const float4*)(p2 + kn + 4);
        #pragma unroll
        for (int d = 0; d < 32; ++d) {
            const float* wr = wb + d * 256 + kc;
            float4 w  = *(const float4*)(wr);
            float4 w2 = *(const float4*)(wr + 4);
            acc0[d] += a0.x*w.x + a0.y*w.y + a0.z*w.z + a0.w*w.w
                     + a0b.x*w2.x + a0b.y*w2.y + a0b.z*w2.z + a0b.w*w2.w;
            acc1[d] += a1.x*w.x + a1.y*w.y + a1.z*w.z + a1.w*w.w
                     + a1b.x*w2.x + a1b.y*w2.y + a1b.z*w2.z + a1b.w*w2.w;
            acc2[d] += a2.x*w.x + a2.y*w.y + a2.z*w.z + a2.w*w.w
                     + a2b.x*w2.x + a2b.y*w2.y + a2b.z*w2.z + a2b.w*w2.w;
        }
    }

    // ---- pair reduce: both lanes get the full row dot ----
    #pragma unroll
    for (int d = 0; d < 32; ++d) {
        acc0[d] += __shfl_xor(acc0[d], 1);
        acc1[d] += __shfl_xor(acc1[d], 1);
        acc2[d] += __shfl_xor(acc2[d], 1);
    }

    // ---- relu + LayerNorm -> X[3][32] (replicated on both lanes) ----
    float X[3][32];
#define LNORM(ACC_, S_)                                                    \
    {                                                                      \
        float sum = 0.f, sq = 0.f;                                         \
        _Pragma("unroll")                                                  \
        for (int d = 0; d < 32; ++d) {                                     \
            float h = fmaxf(ACC_[d] + bp_l[d], 0.f);                       \
            ACC_[d] = h; sum += h; sq += h * h;                            \
        }                                                                  \
        float mu  = sum * 0.03125f;                                        \
        float var = sq * 0.03125f - mu * mu;                               \
        float inv = rsqrtf(var + 1e-5f);                                   \
        _Pragma("unroll")                                                  \
        for (int d = 0; d < 32; ++d)                                       \
            X[S_][d] = g_l[d] * (ACC_[d] - mu) * inv + b_l[d];             \
    }
    LNORM(acc0, 0)
    LNORM(acc1, 1)
    LNORM(acc2, 2)
#undef LNORM

    // ---- scores: sc[s][t] = X_s^T A X_t + u.X_t + v.X_s + c  (replicated, const idx) ----
    float uX[3], vX[3];
    #pragma unroll
    for (int t = 0; t < 3; ++t) {
        float us = 0.f, vs = 0.f;
        #pragma unroll
        for (int e = 0; e < 32; ++e) {
            us += u_l[e] * X[t][e];
            vs += v_l[e] * X[t][e];
        }
        uX[t] = us; vX[t] = vs;
    }
    float sc[3][3];
    #pragma unroll
    for (int t = 0; t < 3; ++t) {
        float Z[32];
        #pragma unroll
        for (int i = 0; i < 32; ++i) {
            const float4* ar = (const float4*)(A_l + i * 32);
            float z = 0.f;
            #pragma unroll
            for (int j = 0; j < 8; ++j) {
                float4 a = ar[j];
                z += DOT4(X[t], j, a);
            }
            Z[i] = z;
        }
        #pragma unroll
        for (int s = 0; s < 3; ++s) {
            float p = 0.f;
            #pragma unroll
            for (int e = 0; e < 32; ++e) p += X[s][e] * Z[e];
            sc[s][t] = p + uX[t] + vX[s] + c_l;
        }
    }

    // ---- softmax rows; g_t = (1/3) sum_s w[s][t] ----
    float g0 = 0.f, g1 = 0.f, g2 = 0.f;
    #pragma unroll
    for (int s = 0; s < 3; ++s) {
        float m  = fmaxf(sc[s][0], fmaxf(sc[s][1], sc[s][2]));
        float e0 = __expf(sc[s][0] - m), e1 = __expf(sc[s][1] - m), e2 = __expf(sc[s][2] - m);
        float r  = 1.f / (e0 + e1 + e2);
        g0 += e0 * r; g1 += e1 * r; g2 += e2 * r;
    }
    g0 *= (1.f / 3.f); g1 *= (1.f / 3.f); g2 *= (1.f / 3.f);

    // xb = g0*X0 + g1*X1 + g2*X2  (softmax rows sum to 1 -> V fold)
    float xb[32];
    #pragma unroll
    for (int e = 0; e < 32; ++e)
        xb[e] = g0 * X[0][e] + g1 * X[1][e] + g2 * X[2][e];

#define MATVEC(W_, BIAS_, IN_, OUT_)                                       \
    _Pragma("unroll")                                                      \
    for (int d = 0; d < 32; ++d) {                                         \
        const float4* wr = (const float4*)(W_ + d * 32);                   \
        float p = BIAS_[d];                                                \
        _Pragma("unroll")                                                  \
        for (int j = 0; j < 8; ++j) {                                      \
            float4 w = wr[j];                                              \
            p += DOT4(IN_, j, w);                                          \
        }                                                                  \
        OUT_[d] = p;                                                       \
    }

    // pooled = xb @ Wv^T + bv
    float pooled[32];
    MATVEC(Wv_l, bv_l, xb, pooled)

    // h1 = relu(pooled @ Wo1^T + bo1)
    float h1[32];
    MATVEC(Wo1_l, bo1_l, pooled, h1)
    #pragma unroll
    for (int d = 0; d < 32; ++d) h1[d] = fmaxf(h1[d], 0.f);

    // o = h1 @ Wo2^T + bo2 + pooled
    float o[32];
    MATVEC(Wo2_l, bo2_l, h1, o)
    #pragma unroll
    for (int d = 0; d < 32; ++d) o[d] += pooled[d];
#undef MATVEC

    // ---- store: each lane writes its half with COMPILE-TIME indices ----
    float4* op = (float4*)(out + (size_t)row * 32);
    if (half == 0) {
        op[0] = make_float4(o[0],  o[1],  o[2],  o[3]);
        op[1] = make_float4(o[4],  o[5],  o[6],  o[7]);
        op[2] = make_float4(o[8],  o[9],  o[10], o[11]);
        op[3] = make_float4(o[12], o[13], o[14], o[15]);
    } else {
        op[4] = make_float4(o[16], o[17], o[18], o[19]);
        op[5] = make_float4(o[20], o[21], o[22], o[23]);
        op[6] = make_float4(o[24], o[25], o[26], o[27]);
        op[7] = make_float4(o[28], o[29], o[30], o[31]);
    }
}

extern "C" void kernel_launch(void* const* d_in, const int* in_sizes, int n_in,
                              void* d_out, int out_size, void* d_ws, size_t ws_size,
                              hipStream_t stream) {
    const float* f1   = (const float*)d_in[0];
    const float* f4   = (const float*)d_in[1];
    const float* fD   = (const float*)d_in[2];
    const float* Wp   = (const float*)d_in[3];
    const float* bp   = (const float*)d_in[4];
    const float* ln_g = (const float*)d_in[5];
    const float* ln_b = (const float*)d_in[6];
    const float* Wq   = (const float*)d_in[7];
    const float* bq   = (const float*)d_in[8];
    const float* Wk   = (const float*)d_in[9];
    const float* bk   = (const float*)d_in[10];
    const float* Wv   = (const float*)d_in[11];
    const float* bv   = (const float*)d_in[12];
    const float* Wo1  = (const float*)d_in[13];
    const float* bo1  = (const float*)d_in[14];
    const float* Wo2  = (const float*)d_in[15];
    const float* bo2  = (const float*)d_in[16];

    const int nRows  = in_sizes[0] / 256;
    const int blocks = (nRows + RPB - 1) / RPB;

    msfe_kernel<<<blocks, BLOCK, 0, stream>>>(
        f1, f4, fD, Wp, bp, ln_g, ln_b, Wq, bq, Wk, bk, Wv, bv,
        Wo1, bo1, Wo2, bo2, (float*)d_out, nRows);
}

// Round 5
// 418.552 us; speedup vs baseline: 1.9653x; 1.9398x over previous
//
#include <hip/hip_runtime.h>

#define BLOCK 256
#define RPB 128   // rows per block (2 threads per row)

// dot of float4 W_ with 4 consecutive elems of X_ starting at 4*J_ (compile-time)
#define DOT4(X_, J_, W_) (X_[4*(J_)]*W_.x + X_[4*(J_)+1]*W_.y + X_[4*(J_)+2]*W_.z + X_[4*(J_)+3]*W_.w)

__launch_bounds__(BLOCK, 1)
__global__ void msfe_kernel(
    const float* __restrict__ f1, const float* __restrict__ f4, const float* __restrict__ fD,
    const float* __restrict__ Wp, const float* __restrict__ bp,
    const float* __restrict__ ln_g, const float* __restrict__ ln_b,
    const float* __restrict__ Wq, const float* __restrict__ bq,
    const float* __restrict__ Wk, const float* __restrict__ bk,
    const float* __restrict__ Wv, const float* __restrict__ bv,
    const float* __restrict__ Wo1, const float* __restrict__ bo1,
    const float* __restrict__ Wo2, const float* __restrict__ bo2,
    float* __restrict__ out, int nRows)
{
    __shared__ float Wp_l[8192];
    __shared__ float Wq_l[1024], Wk_l[1024], A_l[1024];
    __shared__ float Wv_l[1024], Wo1_l[1024], Wo2_l[1024];
    __shared__ float bp_l[32], g_l[32], b_l[32], u_l[32], v_l[32];
    __shared__ float bv_l[32], bo1_l[32], bo2_l[32];
    __shared__ float c_l;

    const int tid = threadIdx.x;

    // ---- stage weights (coalesced float4) ----
    #pragma unroll
    for (int i = 0; i < 8; ++i)
        ((float4*)Wp_l)[tid + i * BLOCK] = ((const float4*)Wp)[tid + i * BLOCK];
    ((float4*)Wq_l)[tid]  = ((const float4*)Wq)[tid];
    ((float4*)Wk_l)[tid]  = ((const float4*)Wk)[tid];
    ((float4*)Wv_l)[tid]  = ((const float4*)Wv)[tid];
    ((float4*)Wo1_l)[tid] = ((const float4*)Wo1)[tid];
    ((float4*)Wo2_l)[tid] = ((const float4*)Wo2)[tid];
    if (tid < 32) {
        bp_l[tid] = bp[tid]; g_l[tid] = ln_g[tid]; b_l[tid] = ln_b[tid];
        bv_l[tid] = bv[tid]; bo1_l[tid] = bo1[tid]; bo2_l[tid] = bo2[tid];
    }
    __syncthreads();

    // ---- build scaled attention matrices: A = Wq^T Wk /sqrt(D), u, v, c ----
    const float isq = 0.17677669529663688f; // 1/sqrt(32)
    {
        const int i = tid & 31, jb = (tid >> 5) * 4;
        float s0 = 0.f, s1 = 0.f, s2 = 0.f, s3 = 0.f;
        #pragma unroll
        for (int d = 0; d < 32; ++d) {
            float wq = Wq_l[d * 32 + i];
            s0 += wq * Wk_l[d * 32 + jb];
            s1 += wq * Wk_l[d * 32 + jb + 1];
            s2 += wq * Wk_l[d * 32 + jb + 2];
            s3 += wq * Wk_l[d * 32 + jb + 3];
        }
        A_l[i * 32 + jb]     = s0 * isq;
        A_l[i * 32 + jb + 1] = s1 * isq;
        A_l[i * 32 + jb + 2] = s2 * isq;
        A_l[i * 32 + jb + 3] = s3 * isq;
    }
    if (tid < 32) {
        float s = 0.f;
        #pragma unroll
        for (int d = 0; d < 32; ++d) s += bq[d] * Wk_l[d * 32 + tid];
        u_l[tid] = s * isq;
    } else if (tid < 64) {
        const int i = tid - 32; float s = 0.f;
        #pragma unroll
        for (int d = 0; d < 32; ++d) s += Wq_l[d * 32 + i] * bk[d];
        v_l[i] = s * isq;
    } else if (tid == 64) {
        float s = 0.f;
        #pragma unroll
        for (int d = 0; d < 32; ++d) s += bq[d] * bk[d];
        c_l = s * isq;
    }
    __syncthreads();

    const int row   = blockIdx.x * RPB + (tid >> 1);
    const int half  = tid & 1;
    const int dbase = half << 4;   // my output-half base   (LDS/global addressing only)
    const int obase = dbase ^ 16;  // partner's output-half base
    const int khalf = half << 7;   // my k-half base
    if (row >= nRows) return;

    const float* __restrict__ p0 = f1 + (size_t)row * 256 + khalf;
    const float* __restrict__ p1 = f4 + (size_t)row * 256 + khalf;
    const float* __restrict__ p2 = fD + (size_t)row * 256 + khalf;

    // ---- Phase A: partial proj over my 128 k-elems, both output halves ----
    // accL[s][e]: d = dbase+e ; accH[s][e]: d = obase+e   (e is compile-time)
    float accL[3][16], accH[3][16];
    #pragma unroll
    for (int s = 0; s < 3; ++s)
        #pragma unroll
        for (int e = 0; e < 16; ++e) { accL[s][e] = 0.f; accH[s][e] = 0.f; }

    float4 n0a = *(const float4*)(p0),     n0b = *(const float4*)(p0 + 4);
    float4 n1a = *(const float4*)(p1),     n1b = *(const float4*)(p1 + 4);
    float4 n2a = *(const float4*)(p2),     n2b = *(const float4*)(p2 + 4);
    #pragma unroll 1
    for (int kc = 0; kc < 128; kc += 8) {
        float4 a0 = n0a, a0b = n0b, a1 = n1a, a1b = n1b, a2 = n2a, a2b = n2b;
        const int kn = (kc + 8 < 128) ? kc + 8 : kc;  // last iter reloads (L1 hit)
        n0a = *(const float4*)(p0 + kn); n0b = *(const float4*)(p0 + kn + 4);
        n1a = *(const float4*)(p1 + kn); n1b = *(const float4*)(p1 + kn + 4);
        n2a = *(const float4*)(p2 + kn); n2b = *(const float4*)(p2 + kn + 4);
        #pragma unroll
        for (int e = 0; e < 16; ++e) {
            const float* wrL = &Wp_l[(dbase + e) * 256 + khalf + kc];
            float4 wl0 = *(const float4*)(wrL);
            float4 wl1 = *(const float4*)(wrL + 4);
            accL[0][e] += a0.x*wl0.x + a0.y*wl0.y + a0.z*wl0.z + a0.w*wl0.w
                        + a0b.x*wl1.x + a0b.y*wl1.y + a0b.z*wl1.z + a0b.w*wl1.w;
            accL[1][e] += a1.x*wl0.x + a1.y*wl0.y + a1.z*wl0.z + a1.w*wl0.w
                        + a1b.x*wl1.x + a1b.y*wl1.y + a1b.z*wl1.z + a1b.w*wl1.w;
            accL[2][e] += a2.x*wl0.x + a2.y*wl0.y + a2.z*wl0.z + a2.w*wl0.w
                        + a2b.x*wl1.x + a2b.y*wl1.y + a2b.z*wl1.z + a2b.w*wl1.w;
            const float* wrH = &Wp_l[(obase + e) * 256 + khalf + kc];
            float4 wh0 = *(const float4*)(wrH);
            float4 wh1 = *(const float4*)(wrH + 4);
            accH[0][e] += a0.x*wh0.x + a0.y*wh0.y + a0.z*wh0.z + a0.w*wh0.w
                        + a0b.x*wh1.x + a0b.y*wh1.y + a0b.z*wh1.z + a0b.w*wh1.w;
            accH[1][e] += a1.x*wh0.x + a1.y*wh0.y + a1.z*wh0.z + a1.w*wh0.w
                        + a1b.x*wh1.x + a1b.y*wh1.y + a1b.z*wh1.z + a1b.w*wh1.w;
            accH[2][e] += a2.x*wh0.x + a2.y*wh0.y + a2.z*wh0.z + a2.w*wh0.w
                        + a2b.x*wh1.x + a2b.y*wh1.y + a2b.z*wh1.z + a2b.w*wh1.w;
        }
    }

    // ---- pair-reduce (k-halves + output-halves) + relu + LN -> Xh[3][16] ----
    // full[d=dbase+e] = accL[e](my k-half) + partner.accH[e](their k-half, same d)
    float Xh[3][16];
    #pragma unroll
    for (int s = 0; s < 3; ++s) {
        float fe[16];
        #pragma unroll
        for (int e = 0; e < 16; ++e)
            fe[e] = accL[s][e] + __shfl_xor(accH[s][e], 1);
        float sm = 0.f, sq = 0.f;
        #pragma unroll
        for (int e = 0; e < 16; ++e) {
            float h = fmaxf(fe[e] + bp_l[dbase + e], 0.f);
            fe[e] = h; sm += h; sq += h * h;
        }
        sm += __shfl_xor(sm, 1);
        sq += __shfl_xor(sq, 1);
        float mu  = sm * 0.03125f;
        float var = sq * 0.03125f - mu * mu;
        float inv = rsqrtf(var + 1e-5f);
        #pragma unroll
        for (int e = 0; e < 16; ++e)
            Xh[s][e] = g_l[dbase + e] * (fe[e] - mu) * inv + b_l[dbase + e];
    }

    // ---- scores: sc[s][t] = X_s^T A X_t + u.X_t + v.X_s + c ----
    float uX[3], vX[3];
    #pragma unroll
    for (int t = 0; t < 3; ++t) {
        float us = 0.f, vs = 0.f;
        #pragma unroll
        for (int e = 0; e < 16; ++e) {
            float x = Xh[t][e];
            us += u_l[dbase + e] * x;
            vs += v_l[dbase + e] * x;
        }
        us += __shfl_xor(us, 1);
        vs += __shfl_xor(vs, 1);
        uX[t] = us; vX[t] = vs;
    }

    float sc[3][3];
    #pragma unroll
    for (int t = 0; t < 3; ++t) {
        // partial Z over my j-half, for all 32 i (split as my/partner i-half)
        float ZL[16], ZH[16];
        #pragma unroll
        for (int e = 0; e < 16; ++e) {
            const float4* arL = (const float4*)&A_l[(dbase + e) * 32 + dbase];
            const float4* arH = (const float4*)&A_l[(obase + e) * 32 + dbase];
            float zl = 0.f, zh = 0.f;
            #pragma unroll
            for (int j = 0; j < 4; ++j) {
                float4 aL = arL[j], aH = arH[j];
                zl += DOT4(Xh[t], j, aL);
                zh += DOT4(Xh[t], j, aH);
            }
            ZL[e] = zl; ZH[e] = zh;
        }
        #pragma unroll
        for (int e = 0; e < 16; ++e)
            ZL[e] += __shfl_xor(ZH[e], 1);   // full Z for i = dbase+e
        #pragma unroll
        for (int s = 0; s < 3; ++s) {
            float p = 0.f;
            #pragma unroll
            for (int e = 0; e < 16; ++e) p += Xh[s][e] * ZL[e];
            sc[s][t] = p;                     // partial over my i-half
        }
    }
    #pragma unroll
    for (int s = 0; s < 3; ++s)
        #pragma unroll
        for (int t = 0; t < 3; ++t) {
            float p = sc[s][t];
            p += __shfl_xor(p, 1);
            sc[s][t] = p + uX[t] + vX[s] + c_l;
        }

    // ---- softmax rows; g_t = (1/3) sum_s w[s][t]  (replicated scalars) ----
    float g0 = 0.f, g1 = 0.f, g2 = 0.f;
    #pragma unroll
    for (int s = 0; s < 3; ++s) {
        float m  = fmaxf(sc[s][0], fmaxf(sc[s][1], sc[s][2]));
        float e0 = __expf(sc[s][0] - m), e1 = __expf(sc[s][1] - m), e2 = __expf(sc[s][2] - m);
        float r  = 1.f / (e0 + e1 + e2);
        g0 += e0 * r; g1 += e1 * r; g2 += e2 * r;
    }
    g0 *= (1.f / 3.f); g1 *= (1.f / 3.f); g2 *= (1.f / 3.f);

    // xb half (softmax rows sum to 1 -> V fold)
    float xbh[16];
    #pragma unroll
    for (int e = 0; e < 16; ++e)
        xbh[e] = g0 * Xh[0][e] + g1 * Xh[1][e] + g2 * Xh[2][e];

    // half-input matvec: OUT_[e] (d=dbase+e, full) from IN_ = my input half
#define MATVEC_H(W_, B_, IN_, OUT_)                                        \
    {                                                                      \
        float PL[16], PH[16];                                              \
        _Pragma("unroll")                                                  \
        for (int e = 0; e < 16; ++e) {                                     \
            const float4* wL = (const float4*)&W_[(dbase + e) * 32 + dbase];\
            const float4* wH = (const float4*)&W_[(obase + e) * 32 + dbase];\
            float pl = 0.f, ph = 0.f;                                      \
            _Pragma("unroll")                                              \
            for (int j = 0; j < 4; ++j) {                                  \
                float4 l = wL[j], h = wH[j];                               \
                pl += DOT4(IN_, j, l);                                     \
                ph += DOT4(IN_, j, h);                                     \
            }                                                              \
            PL[e] = pl; PH[e] = ph;                                        \
        }                                                                  \
        _Pragma("unroll")                                                  \
        for (int e = 0; e < 16; ++e)                                       \
            OUT_[e] = PL[e] + __shfl_xor(PH[e], 1) + B_[dbase + e];        \
    }

    float ph16[16];
    MATVEC_H(Wv_l, bv_l, xbh, ph16)           // pooled half

    float hh16[16];
    MATVEC_H(Wo1_l, bo1_l, ph16, hh16)        // pre-relu h1 half
    #pragma unroll
    for (int e = 0; e < 16; ++e) hh16[e] = fmaxf(hh16[e], 0.f);

    float oh16[16];
    MATVEC_H(Wo2_l, bo2_l, hh16, oh16)        // o half
    #pragma unroll
    for (int e = 0; e < 16; ++e) oh16[e] += ph16[e];
#undef MATVEC_H

    // ---- store my half (coalesced: pair covers the row) ----
    float4* op = (float4*)(out + (size_t)row * 32 + dbase);
    #pragma unroll
    for (int j = 0; j < 4; ++j)
        op[j] = make_float4(oh16[4*j], oh16[4*j+1], oh16[4*j+2], oh16[4*j+3]);
}

extern "C" void kernel_launch(void* const* d_in, const int* in_sizes, int n_in,
                              void* d_out, int out_size, void* d_ws, size_t ws_size,
                              hipStream_t stream) {
    const float* f1   = (const float*)d_in[0];
    const float* f4   = (const float*)d_in[1];
    const float* fD   = (const float*)d_in[2];
    const float* Wp   = (const float*)d_in[3];
    const float* bp   = (const float*)d_in[4];
    const float* ln_g = (const float*)d_in[5];
    const float* ln_b = (const float*)d_in[6];
    const float* Wq   = (const float*)d_in[7];
    const float* bq   = (const float*)d_in[8];
    const float* Wk   = (const float*)d_in[9];
    const float* bk   = (const float*)d_in[10];
    const float* Wv   = (const float*)d_in[11];
    const float* bv   = (const float*)d_in[12];
    const float* Wo1  = (const float*)d_in[13];
    const float* bo1  = (const float*)d_in[14];
    const float* Wo2  = (const float*)d_in[15];
    const float* bo2  = (const float*)d_in[16];

    const int nRows  = in_sizes[0] / 256;
    const int blocks = (nRows + RPB - 1) / RPB;

    msfe_kernel<<<blocks, BLOCK, 0, stream>>>(
        f1, f4, fD, Wp, bp, ln_g, ln_b, Wq, bq, Wk, bk, Wv, bv,
        Wo1, bo1, Wo2, bo2, (float*)d_out, nRows);
}